// Round 13
// baseline (3418.278 us; speedup 1.0000x reference)
//
#include <hip/hip_runtime.h>
#include <hip/hip_bf16.h>

#define BTOT 16384

typedef __attribute__((ext_vector_type(8))) short bf16x8;
typedef __attribute__((ext_vector_type(4))) float f32x4;

__device__ __forceinline__ float sig_(float x) {
    return __fdividef(1.0f, 1.0f + __expf(-x));
}
__device__ __forceinline__ float tanh_(float x) {
    float ax = fabsf(x);
    float e  = __expf(-2.0f * ax);
    float r  = __fdividef(1.0f - e, 1.0f + e);
    return x < 0.0f ? -r : r;
}

// ---------------------------------------------------------------------------
// Kernel 0a: MFMA B-fragments for k_mid. W[416][800]: rows 0-199 Wih^T,
// 200-399 Whh^T, 400-414 zero, 415 bias. o' = u*4+g. NEW order [kt][ct]:
// e = ((kt*50+ct)*64 + lane)*8 + j; k = kt*32+(lane>>4)*8+j; o' = ct*16+(lane&15).
// ---------------------------------------------------------------------------
__global__ __launch_bounds__(256) void k_prep_mfma(
    const float* __restrict__ Wih, const float* __restrict__ Whh,
    const float* __restrict__ bih, const float* __restrict__ bhh,
    __hip_bfloat16* __restrict__ Bhi, __hip_bfloat16* __restrict__ Blo)
{
    const int e = blockIdx.x * 256 + threadIdx.x;
    if (e >= 332800) return;
    const int j  = e & 7;
    const int l  = (e >> 3) & 63;
    const int r2 = e >> 9;             // kt*50 + ct
    const int ct = r2 % 50;
    const int kt = r2 / 50;
    const int k  = kt * 32 + ((l >> 4) << 3) + j;
    const int op = ct * 16 + (l & 15);
    const int u  = op >> 2;
    const int g  = op & 3;
    const int row = g * 200 + u;
    float val;
    if (k < 200)       val = Wih[(size_t)row * 200 + k];
    else if (k < 400)  val = Whh[(size_t)row * 200 + (k - 200)];
    else if (k == 415) val = bih[row] + bhh[row];
    else               val = 0.0f;
    const __hip_bfloat16 hi = __float2bfloat16(val);
    Bhi[e] = hi;
    Blo[e] = __float2bfloat16(val - __bfloat162float(hi));
}

// ---------------------------------------------------------------------------
// Kernel 0b (PROVEN): MFMA B-fragments for the 100-LSTMs. W[128][400]:
// A cols 0-4 x_hi, 5-9 x_lo, 10-109 h, 110 bias, 111-127 zero.
// e = ((ct*4+kt)*64 + lane)*8 + j. n = 51,200.
// ---------------------------------------------------------------------------
__global__ __launch_bounds__(256) void k_prep_mfma100(
    const float* __restrict__ Wih, const float* __restrict__ Whh,
    const float* __restrict__ bih, const float* __restrict__ bhh,
    __hip_bfloat16* __restrict__ Bhi, __hip_bfloat16* __restrict__ Blo)
{
    const int e = blockIdx.x * 256 + threadIdx.x;
    if (e >= 51200) return;
    const int j  = e & 7;
    const int l  = (e >> 3) & 63;
    const int r2 = e >> 9;             // ct*4 + kt
    const int kt = r2 & 3;
    const int ct = r2 >> 2;
    const int k  = kt * 32 + ((l >> 4) << 3) + j;
    const int op = ct * 16 + (l & 15);
    const int u  = op >> 2;
    const int g  = op & 3;
    const int row = g * 100 + u;
    float val;
    if (k < 5)         val = Wih[(size_t)row * 5 + k];
    else if (k < 10)   val = Wih[(size_t)row * 5 + (k - 5)];
    else if (k < 110)  val = Whh[(size_t)row * 100 + (k - 10)];
    else if (k == 110) val = bih[row] + bhh[row];
    else               val = 0.0f;
    const __hip_bfloat16 hi = __float2bfloat16(val);
    Bhi[e] = hi;
    Blo[e] = __float2bfloat16(val - __bfloat162float(hi));
}

// ---------------------------------------------------------------------------
// Kernel 1 (round-12 PROVEN, verbatim): MFMA 100-LSTMs. grid (256,2), 512 thr.
// ---------------------------------------------------------------------------
__global__ __launch_bounds__(512, 2) void k_lstm100(
    const float* __restrict__ x,
    const float* __restrict__ h0f, const float* __restrict__ c0f,
    const float* __restrict__ h0b, const float* __restrict__ c0b,
    const __hip_bfloat16* __restrict__ BFhi, const __hip_bfloat16* __restrict__ BFlo,
    const __hip_bfloat16* __restrict__ BBhi, const __hip_bfloat16* __restrict__ BBlo,
    __hip_bfloat16* __restrict__ HF, __hip_bfloat16* __restrict__ HB)
{
    __shared__ __hip_bfloat16 At[64][136];
    __shared__ float scr[8][16][17];

    const int dir = blockIdx.y;
    const float* h0 = dir ? h0b : h0f;
    const float* c0 = dir ? c0b : c0f;
    const __hip_bfloat16* Bhi = dir ? BBhi : BFhi;
    const __hip_bfloat16* Blo = dir ? BBlo : BFlo;
    __hip_bfloat16* Hout = dir ? HB : HF;

    const int tid = threadIdx.x;
    const int l   = tid & 63;
    const int w   = tid >> 6;
    const int rb  = blockIdx.x * 64;

    float cst[4][4];
    #pragma unroll
    for (int cti = 0; cti < 4; ++cti) {
        const int ct = w + 8 * cti;
        if (ct < 25) {
            #pragma unroll
            for (int rt = 0; rt < 4; ++rt)
                cst[cti][rt] = c0[(size_t)(rb + rt * 16 + (l >> 2)) * 100 + ct * 4 + (l & 3)];
        }
    }

    for (int i = tid; i < 6400; i += 512) {
        const int row = i / 100, u = i - row * 100;
        At[row][10 + u] = __float2bfloat16(h0[(size_t)(rb + row) * 100 + u]);
    }
    for (int i = tid; i < 64 * 26; i += 512) {
        const int row = i / 26, cc = i - row * 26;
        At[row][110 + cc] = __float2bfloat16(cc == 0 ? 1.0f : 0.0f);
    }
    {
        const int tt0 = dir ? 19 : 0;
        if (tid < 320) {
            const float v = x[(size_t)tt0 * (BTOT * 5) + (size_t)rb * 5 + tid];
            const int row = tid / 5, cc = tid - row * 5;
            const __hip_bfloat16 hi = __float2bfloat16(v);
            At[row][cc]     = hi;
            At[row][5 + cc] = __float2bfloat16(v - __bfloat162float(hi));
        }
    }
    __syncthreads();

    for (int t = 0; t < 20; ++t) {
        const int tt = dir ? (19 - t) : t;

        f32x4 acc[4][4];
        #pragma unroll
        for (int cti = 0; cti < 4; ++cti)
            #pragma unroll
            for (int rt = 0; rt < 4; ++rt)
                acc[cti][rt] = (f32x4){0.f, 0.f, 0.f, 0.f};

        #pragma unroll
        for (int kt = 0; kt < 4; ++kt) {
            bf16x8 afr[4];
            #pragma unroll
            for (int rt = 0; rt < 4; ++rt)
                afr[rt] = *reinterpret_cast<const bf16x8*>(
                    &At[rt * 16 + (l & 15)][kt * 32 + (l >> 4) * 8]);
            #pragma unroll
            for (int cti = 0; cti < 4; ++cti) {
                const int ct = w + 8 * cti;
                if (ct < 25) {
                    const size_t fo = ((size_t)(ct * 4 + kt) * 64 + l) * 8;
                    const bf16x8 bh = *reinterpret_cast<const bf16x8*>(Bhi + fo);
                    const bf16x8 bl = *reinterpret_cast<const bf16x8*>(Blo + fo);
                    #pragma unroll
                    for (int rt = 0; rt < 4; ++rt) {
                        acc[cti][rt] = __builtin_amdgcn_mfma_f32_16x16x32_bf16(
                            afr[rt], bh, acc[cti][rt], 0, 0, 0);
                        acc[cti][rt] = __builtin_amdgcn_mfma_f32_16x16x32_bf16(
                            afr[rt], bl, acc[cti][rt], 0, 0, 0);
                    }
                }
            }
        }

        float hval[4][4];
        #pragma unroll
        for (int cti = 0; cti < 4; ++cti) {
            const int ct = w + 8 * cti;
            if (ct < 25) {
                #pragma unroll
                for (int rt = 0; rt < 4; ++rt) {
                    #pragma unroll
                    for (int rr = 0; rr < 4; ++rr)
                        scr[w][(l >> 4) * 4 + rr][l & 15] = acc[cti][rt][rr];
                    const float g0 = scr[w][l >> 2][(l & 3) * 4 + 0];
                    const float g1 = scr[w][l >> 2][(l & 3) * 4 + 1];
                    const float g2 = scr[w][l >> 2][(l & 3) * 4 + 2];
                    const float g3 = scr[w][l >> 2][(l & 3) * 4 + 3];
                    const float ig = sig_(g0);
                    const float fg = sig_(g1);
                    const float gg = tanh_(g2);
                    const float og = sig_(g3);
                    const float cn = fmaf(fg, cst[cti][rt], ig * gg);
                    cst[cti][rt] = cn;
                    hval[cti][rt] = og * tanh_(cn);
                }
            }
        }
        __syncthreads();

        #pragma unroll
        for (int cti = 0; cti < 4; ++cti) {
            const int ct = w + 8 * cti;
            if (ct < 25) {
                #pragma unroll
                for (int rt = 0; rt < 4; ++rt) {
                    const __hip_bfloat16 hb = __float2bfloat16(hval[cti][rt]);
                    At[rt * 16 + (l >> 2)][10 + ct * 4 + (l & 3)] = hb;
                    Hout[((size_t)tt * 100 + ct * 4 + (l & 3)) * BTOT
                         + rb + rt * 16 + (l >> 2)] = hb;
                }
            }
        }
        if (t < 19) {
            const int ttn = dir ? (19 - (t + 1)) : (t + 1);
            if (tid < 320) {
                const float v = x[(size_t)ttn * (BTOT * 5) + (size_t)rb * 5 + tid];
                const int row = tid / 5, cc = tid - row * 5;
                const __hip_bfloat16 hi = __float2bfloat16(v);
                At[row][cc]     = hi;
                At[row][5 + cc] = __float2bfloat16(v - __bfloat162float(hi));
            }
        }
        __syncthreads();
    }
}

// ---------------------------------------------------------------------------
// Kernel 2 v2: MFMA middle LSTM, fragment-order A-tile (conflict-free reads)
// + kt-outer loop (A loaded once per kt). grid 256, block 512 (8 waves).
// Af[rt][kt][lane][8] holds A element (row = rt*16+(lane&15),
// c = kt*32+(lane>>4)*8+e). idx(row,c) maps writes. LDS = 61,952 B.
// ---------------------------------------------------------------------------
__device__ __forceinline__ int aidx(int row, int c) {
    return (((row >> 4) * 13 + (c >> 5)) * 64 + ((c >> 3) & 3) * 16 + (row & 15)) * 8
           + (c & 7);
}

__global__ __launch_bounds__(512, 2) void k_mid(
    const float* __restrict__ h0m, const float* __restrict__ c0m,
    const __hip_bfloat16* __restrict__ Bhi, const __hip_bfloat16* __restrict__ Blo,
    const __hip_bfloat16* __restrict__ HF, const __hip_bfloat16* __restrict__ HB,
    __hip_bfloat16* __restrict__ HM)
{
    __shared__ __hip_bfloat16 Af[4][13][64][8];   // 53,248 B
    __shared__ float scr[8][16][17];              //  8,704 B

    const int tid = threadIdx.x;
    const int l   = tid & 63;
    const int w   = tid >> 6;
    const int rb  = blockIdx.x * 64;
    __hip_bfloat16* A = &Af[0][0][0][0];

    float cst[7][4], hval[7][4];
    #pragma unroll
    for (int cti = 0; cti < 7; ++cti) {
        const int ct = w + 8 * cti;
        if (ct < 50) {
            #pragma unroll
            for (int rt = 0; rt < 4; ++rt) {
                const int row = rb + rt * 16 + (l >> 2);
                cst[cti][rt] = c0m[(size_t)row * 200 + ct * 4 + (l & 3)];
            }
        }
    }

    // init A: hm = bf16(h0m) (cols 200-399); pads (400-415); hf/hb[0] (0-199)
    for (int i = tid; i < 12800; i += 512) {
        const int u = i % 200, rr = i / 200;
        A[aidx(rr, 200 + u)] = __float2bfloat16(h0m[(size_t)(rb + rr) * 200 + u]);
    }
    for (int i = tid; i < 1024; i += 512) {
        const int rr = i >> 4, cc = i & 15;
        A[aidx(rr, 400 + cc)] = __float2bfloat16((cc == 15) ? 1.0f : 0.0f);
    }
    for (int i = tid; i < 6400; i += 512) {
        const int rr = i & 63, u = i >> 6;
        A[aidx(rr, u)]       = HF[(size_t)u * BTOT + rb + rr];
        A[aidx(rr, 100 + u)] = HB[(size_t)u * BTOT + rb + rr];
    }
    __syncthreads();

    for (int t = 0; t < 20; ++t) {
        f32x4 acc[7][4];
        #pragma unroll
        for (int cti = 0; cti < 7; ++cti)
            #pragma unroll
            for (int rt = 0; rt < 4; ++rt)
                acc[cti][rt] = (f32x4){0.f, 0.f, 0.f, 0.f};

        #pragma unroll
        for (int kt = 0; kt < 13; ++kt) {
            bf16x8 afr[4];
            #pragma unroll
            for (int rt = 0; rt < 4; ++rt)
                afr[rt] = *reinterpret_cast<const bf16x8*>(&Af[rt][kt][l][0]);
            #pragma unroll
            for (int cti = 0; cti < 7; ++cti) {
                const int ct = w + 8 * cti;
                if (ct < 50) {
                    const size_t fo = ((size_t)(kt * 50 + ct) * 64 + l) * 8;
                    const bf16x8 bh = *reinterpret_cast<const bf16x8*>(Bhi + fo);
                    const bf16x8 bl = *reinterpret_cast<const bf16x8*>(Blo + fo);
                    #pragma unroll
                    for (int rt = 0; rt < 4; ++rt) {
                        acc[cti][rt] = __builtin_amdgcn_mfma_f32_16x16x32_bf16(
                            afr[rt], bh, acc[cti][rt], 0, 0, 0);
                        acc[cti][rt] = __builtin_amdgcn_mfma_f32_16x16x32_bf16(
                            afr[rt], bl, acc[cti][rt], 0, 0, 0);
                    }
                }
            }
        }

        // gates (per-wave transpose scratch, proven pattern)
        #pragma unroll
        for (int cti = 0; cti < 7; ++cti) {
            const int ct = w + 8 * cti;
            if (ct < 50) {
                #pragma unroll
                for (int rt = 0; rt < 4; ++rt) {
                    #pragma unroll
                    for (int rr = 0; rr < 4; ++rr)
                        scr[w][(l >> 4) * 4 + rr][l & 15] = acc[cti][rt][rr];
                    const float g0 = scr[w][l >> 2][(l & 3) * 4 + 0];
                    const float g1 = scr[w][l >> 2][(l & 3) * 4 + 1];
                    const float g2 = scr[w][l >> 2][(l & 3) * 4 + 2];
                    const float g3 = scr[w][l >> 2][(l & 3) * 4 + 3];
                    const float ig = sig_(g0);
                    const float fg = sig_(g1);
                    const float gg = tanh_(g2);
                    const float og = sig_(g3);
                    const float cn = fmaf(fg, cst[cti][rt], ig * gg);
                    cst[cti][rt] = cn;
                    hval[cti][rt] = og * tanh_(cn);
                }
            }
        }
        __syncthreads();           // all waves done reading A for step t

        // publish hm[t] into A cols 200-399
        #pragma unroll
        for (int cti = 0; cti < 7; ++cti) {
            const int ct = w + 8 * cti;
            if (ct < 50) {
                #pragma unroll
                for (int rt = 0; rt < 4; ++rt)
                    A[aidx(rt * 16 + (l >> 2), 200 + ct * 4 + (l & 3))] =
                        __float2bfloat16(hval[cti][rt]);
            }
        }
        // stage hf/hb[t+1] into cols 0-199
        if (t < 19) {
            const __hip_bfloat16* HFt = HF + (size_t)(t + 1) * 100 * BTOT + rb;
            const __hip_bfloat16* HBt = HB + (size_t)(t + 1) * 100 * BTOT + rb;
            for (int i = tid; i < 6400; i += 512) {
                const int rr = i & 63, u = i >> 6;
                A[aidx(rr, u)]       = HFt[(size_t)u * BTOT + rr];
                A[aidx(rr, 100 + u)] = HBt[(size_t)u * BTOT + rr];
            }
        }
        __syncthreads();
    }

    // final h -> HM bf16 [b][u]
    for (int i = tid; i < 12800; i += 512) {
        const int u = i % 200, rr = i / 200;
        HM[(size_t)(rb + rr) * 200 + u] = A[aidx(rr, 200 + u)];
    }
}

// ---------------------------------------------------------------------------
// Kernel 3 (PROVEN): dense + convT chain, zero-padded LDS tiles.
// ---------------------------------------------------------------------------
__global__ __launch_bounds__(256, 2) void k_head(
    const __hip_bfloat16* __restrict__ HM,
    const float* __restrict__ Wd, const float* __restrict__ bd,
    const float* __restrict__ w1, const float* __restrict__ b1,
    const float* __restrict__ w2, const float* __restrict__ b2,
    const float* __restrict__ w3, const float* __restrict__ b3,
    const float* __restrict__ g1, const float* __restrict__ be1,
    const float* __restrict__ m1, const float* __restrict__ v1,
    const float* __restrict__ g2, const float* __restrict__ be2,
    const float* __restrict__ m2, const float* __restrict__ v2,
    float* __restrict__ out)
{
    __shared__ float hm_s[200];
    __shared__ float y27p[29];
    __shared__ float t1p[128][58];
    __shared__ float t2p[64][110];
    __shared__ float sc1[128], sh1[128], sc2[64], sh2[64];

    const int tid = threadIdx.x;
    const int b   = blockIdx.x;

    if (tid < 200) hm_s[tid] = __bfloat162float(HM[(size_t)b * 200 + tid]);
    if (tid < 128) {
        const float s = g1[tid] * __frsqrt_rn(v1[tid] + 1e-5f);
        sc1[tid] = s; sh1[tid] = be1[tid] - m1[tid] * s;
    } else if (tid < 192) {
        const int cc = tid - 128;
        const float s = g2[cc] * __frsqrt_rn(v2[cc] + 1e-5f);
        sc2[cc] = s; sh2[cc] = be2[cc] - m2[cc] * s;
    }
    {
        const int co = tid >> 1;
        t1p[co][(tid & 1) ? 55 : 0] = 0.0f;
        if (tid < 128) { t1p[tid][56] = 0.0f; t1p[tid][57] = 0.0f; }
        if (tid < 64)  { t2p[tid][0] = 0.0f; t2p[tid][109] = 0.0f; }
        if (tid == 0)  { y27p[0] = 0.0f; y27p[28] = 0.0f; }
    }
    __syncthreads();

    if (tid < 27) {
        float a = bd[tid];
        const float* wr = Wd + tid * 200;
        for (int i = 0; i < 200; ++i) a = fmaf(hm_s[i], wr[i], a);
        y27p[tid + 1] = a;
    }
    __syncthreads();

    for (int idx = tid; idx < 128 * 54; idx += 256) {
        const int co = idx / 54;
        const int ll = idx - co * 54;
        const int q  = (ll + 1) >> 1;
        const float4 w = *reinterpret_cast<const float4*>(w1 + co * 4);
        const float wHI = (ll & 1) ? w.x : w.y;
        const float wLO = (ll & 1) ? w.z : w.w;
        float a = b1[co];
        a = fmaf(y27p[q + 1], wHI, a);
        a = fmaf(y27p[q],     wLO, a);
        a = fmaf(a, sc1[co], sh1[co]);
        t1p[co][ll + 1] = fmaxf(a, 0.0f);
    }
    __syncthreads();

    {
        const int co   = tid & 63;
        const int lseg = tid >> 6;
        const int l0   = lseg * 28;
        const int qb   = lseg * 14;
        float acc[28];
        const float bb = b2[co];
        #pragma unroll
        for (int j = 0; j < 28; ++j) acc[j] = bb;

        #pragma unroll 2
        for (int ci = 0; ci < 128; ++ci) {
            float tv[16];
            #pragma unroll
            for (int j = 0; j < 16; ++j) tv[j] = t1p[ci][qb + j];
            const float4 w = *reinterpret_cast<const float4*>(
                w2 + ((size_t)((ci << 6) + co) << 2));
            #pragma unroll
            for (int j = 0; j < 28; ++j) {
                const int qi = (j + 1) >> 1;
                const float wHI = (j & 1) ? w.x : w.y;
                const float wLO = (j & 1) ? w.z : w.w;
                acc[j] = fmaf(tv[qi + 1], wHI, acc[j]);
                acc[j] = fmaf(tv[qi],     wLO, acc[j]);
            }
        }
        const float s2 = sc2[co], h2 = sh2[co];
        #pragma unroll
        for (int j = 0; j < 28; ++j) {
            const int ll = l0 + j;
            if (ll < 108) t2p[co][ll + 1] = fmaxf(fmaf(acc[j], s2, h2), 0.0f);
        }
    }
    __syncthreads();

    if (tid < 216) {
        const int ll = tid;
        const int q = (ll + 1) >> 1;
        const bool odd = (ll & 1) != 0;
        float a = b3[0];
        #pragma unroll 4
        for (int ci = 0; ci < 64; ++ci) {
            const float4 w = *reinterpret_cast<const float4*>(w3 + ci * 4);
            const float wHI = odd ? w.x : w.y;
            const float wLO = odd ? w.z : w.w;
            a = fmaf(t2p[ci][q + 1], wHI, a);
            a = fmaf(t2p[ci][q],     wLO, a);
        }
        out[(size_t)b * 216 + ll] = a;
    }
}

// ---------------------------------------------------------------------------
extern "C" void kernel_launch(void* const* d_in, const int* in_sizes, int n_in,
                              void* d_out, int out_size, void* d_ws, size_t ws_size,
                              hipStream_t stream) {
    const float* x     = (const float*)d_in[0];
    const float* h0f   = (const float*)d_in[1];
    const float* c0f   = (const float*)d_in[2];
    const float* h0b   = (const float*)d_in[3];
    const float* c0b   = (const float*)d_in[4];
    const float* h0m   = (const float*)d_in[5];
    const float* c0m   = (const float*)d_in[6];
    const float* Wih_f = (const float*)d_in[7];
    const float* Whh_f = (const float*)d_in[8];
    const float* bih_f = (const float*)d_in[9];
    const float* bhh_f = (const float*)d_in[10];
    const float* Wih_b = (const float*)d_in[11];
    const float* Whh_b = (const float*)d_in[12];
    const float* bih_b = (const float*)d_in[13];
    const float* bhh_b = (const float*)d_in[14];
    const float* Wih_m = (const float*)d_in[15];
    const float* Whh_m = (const float*)d_in[16];
    const float* bih_m = (const float*)d_in[17];
    const float* bhh_m = (const float*)d_in[18];
    const float* Wd    = (const float*)d_in[19];
    const float* bd    = (const float*)d_in[20];
    const float* w1    = (const float*)d_in[21];
    const float* b1    = (const float*)d_in[22];
    const float* w2    = (const float*)d_in[23];
    const float* b2    = (const float*)d_in[24];
    const float* w3    = (const float*)d_in[25];
    const float* b3    = (const float*)d_in[26];
    const float* g1    = (const float*)d_in[27];
    const float* be1   = (const float*)d_in[28];
    const float* m1    = (const float*)d_in[29];
    const float* v1    = (const float*)d_in[30];
    const float* g2    = (const float*)d_in[31];
    const float* be2   = (const float*)d_in[32];
    const float* m2    = (const float*)d_in[33];
    const float* v2    = (const float*)d_in[34];

    // ws layout (bytes), total 139,366,400 <= proven 144,179,200:
    char* ws = (char*)d_ws;
    __hip_bfloat16* HF   = (__hip_bfloat16*)ws;
    __hip_bfloat16* HB   = (__hip_bfloat16*)(ws + 65536000);
    __hip_bfloat16* BhiM = (__hip_bfloat16*)(ws + 131072000);
    __hip_bfloat16* BloM = (__hip_bfloat16*)(ws + 131737600);
    __hip_bfloat16* BFhi = (__hip_bfloat16*)(ws + 132403200);
    __hip_bfloat16* BFlo = (__hip_bfloat16*)(ws + 132505600);
    __hip_bfloat16* BBhi = (__hip_bfloat16*)(ws + 132608000);
    __hip_bfloat16* BBlo = (__hip_bfloat16*)(ws + 132710400);
    __hip_bfloat16* HM   = (__hip_bfloat16*)(ws + 132812800);

    k_prep_mfma<<<(332800 + 255) / 256, 256, 0, stream>>>(
        Wih_m, Whh_m, bih_m, bhh_m, BhiM, BloM);
    k_prep_mfma100<<<(51200 + 255) / 256, 256, 0, stream>>>(
        Wih_f, Whh_f, bih_f, bhh_f, BFhi, BFlo);
    k_prep_mfma100<<<(51200 + 255) / 256, 256, 0, stream>>>(
        Wih_b, Whh_b, bih_b, bhh_b, BBhi, BBlo);

    k_lstm100<<<dim3(256, 2), 512, 0, stream>>>(
        x, h0f, c0f, h0b, c0b,
        BFhi, BFlo, BBhi, BBlo, HF, HB);

    k_mid<<<256, 512, 0, stream>>>(
        h0m, c0m, BhiM, BloM, HF, HB, HM);

    k_head<<<16384, 256, 0, stream>>>(
        HM, Wd, bd, w1, b1, w2, b2, w3, b3,
        g1, be1, m1, v1, g2, be2, m2, v2, (float*)d_out);
}

// Round 14
// 3039.693 us; speedup vs baseline: 1.1245x; 1.1245x over previous
//
#include <hip/hip_runtime.h>
#include <hip/hip_bf16.h>

#define BTOT 16384

typedef __attribute__((ext_vector_type(8))) short bf16x8;
typedef __attribute__((ext_vector_type(4))) float f32x4;

__device__ __forceinline__ float sig_(float x) {
    return __fdividef(1.0f, 1.0f + __expf(-x));
}
__device__ __forceinline__ float tanh_(float x) {
    float ax = fabsf(x);
    float e  = __expf(-2.0f * ax);
    float r  = __fdividef(1.0f - e, 1.0f + e);
    return x < 0.0f ? -r : r;
}

// ---------------------------------------------------------------------------
// Kernel 0a (round-12 PROVEN order): MFMA B-fragments for k_mid. W[416][800]:
// rows 0-199 Wih^T, 200-399 Whh^T, 400-414 zero, 415 bias. o' = u*4+g.
// e = ((ct*13+kt)*64 + lane)*8 + j; k = kt*32+(lane>>4)*8+j; o' = ct*16+(lane&15).
// ---------------------------------------------------------------------------
__global__ __launch_bounds__(256) void k_prep_mfma(
    const float* __restrict__ Wih, const float* __restrict__ Whh,
    const float* __restrict__ bih, const float* __restrict__ bhh,
    __hip_bfloat16* __restrict__ Bhi, __hip_bfloat16* __restrict__ Blo)
{
    const int e = blockIdx.x * 256 + threadIdx.x;
    if (e >= 332800) return;
    const int j  = e & 7;
    const int l  = (e >> 3) & 63;
    const int r2 = e >> 9;             // ct*13 + kt
    const int kt = r2 % 13;
    const int ct = r2 / 13;
    const int k  = kt * 32 + ((l >> 4) << 3) + j;
    const int op = ct * 16 + (l & 15);
    const int u  = op >> 2;
    const int g  = op & 3;
    const int row = g * 200 + u;
    float val;
    if (k < 200)       val = Wih[(size_t)row * 200 + k];
    else if (k < 400)  val = Whh[(size_t)row * 200 + (k - 200)];
    else if (k == 415) val = bih[row] + bhh[row];
    else               val = 0.0f;
    const __hip_bfloat16 hi = __float2bfloat16(val);
    Bhi[e] = hi;
    Blo[e] = __float2bfloat16(val - __bfloat162float(hi));
}

// ---------------------------------------------------------------------------
// Kernel 0b (PROVEN): MFMA B-fragments for the 100-LSTMs. W[128][400]:
// A cols 0-4 x_hi, 5-9 x_lo, 10-109 h, 110 bias, 111-127 zero.
// e = ((ct*4+kt)*64 + lane)*8 + j. n = 51,200.
// ---------------------------------------------------------------------------
__global__ __launch_bounds__(256) void k_prep_mfma100(
    const float* __restrict__ Wih, const float* __restrict__ Whh,
    const float* __restrict__ bih, const float* __restrict__ bhh,
    __hip_bfloat16* __restrict__ Bhi, __hip_bfloat16* __restrict__ Blo)
{
    const int e = blockIdx.x * 256 + threadIdx.x;
    if (e >= 51200) return;
    const int j  = e & 7;
    const int l  = (e >> 3) & 63;
    const int r2 = e >> 9;             // ct*4 + kt
    const int kt = r2 & 3;
    const int ct = r2 >> 2;
    const int k  = kt * 32 + ((l >> 4) << 3) + j;
    const int op = ct * 16 + (l & 15);
    const int u  = op >> 2;
    const int g  = op & 3;
    const int row = g * 100 + u;
    float val;
    if (k < 5)         val = Wih[(size_t)row * 5 + k];
    else if (k < 10)   val = Wih[(size_t)row * 5 + (k - 5)];
    else if (k < 110)  val = Whh[(size_t)row * 100 + (k - 10)];
    else if (k == 110) val = bih[row] + bhh[row];
    else               val = 0.0f;
    const __hip_bfloat16 hi = __float2bfloat16(val);
    Bhi[e] = hi;
    Blo[e] = __float2bfloat16(val - __bfloat162float(hi));
}

// ---------------------------------------------------------------------------
// Kernel 1 (round-12 PROVEN, verbatim): MFMA 100-LSTMs. grid (256,2), 512 thr.
// ---------------------------------------------------------------------------
__global__ __launch_bounds__(512, 2) void k_lstm100(
    const float* __restrict__ x,
    const float* __restrict__ h0f, const float* __restrict__ c0f,
    const float* __restrict__ h0b, const float* __restrict__ c0b,
    const __hip_bfloat16* __restrict__ BFhi, const __hip_bfloat16* __restrict__ BFlo,
    const __hip_bfloat16* __restrict__ BBhi, const __hip_bfloat16* __restrict__ BBlo,
    __hip_bfloat16* __restrict__ HF, __hip_bfloat16* __restrict__ HB)
{
    __shared__ __hip_bfloat16 At[64][136];
    __shared__ float scr[8][16][17];

    const int dir = blockIdx.y;
    const float* h0 = dir ? h0b : h0f;
    const float* c0 = dir ? c0b : c0f;
    const __hip_bfloat16* Bhi = dir ? BBhi : BFhi;
    const __hip_bfloat16* Blo = dir ? BBlo : BFlo;
    __hip_bfloat16* Hout = dir ? HB : HF;

    const int tid = threadIdx.x;
    const int l   = tid & 63;
    const int w   = tid >> 6;
    const int rb  = blockIdx.x * 64;

    float cst[4][4];
    #pragma unroll
    for (int cti = 0; cti < 4; ++cti) {
        const int ct = w + 8 * cti;
        if (ct < 25) {
            #pragma unroll
            for (int rt = 0; rt < 4; ++rt)
                cst[cti][rt] = c0[(size_t)(rb + rt * 16 + (l >> 2)) * 100 + ct * 4 + (l & 3)];
        }
    }

    for (int i = tid; i < 6400; i += 512) {
        const int row = i / 100, u = i - row * 100;
        At[row][10 + u] = __float2bfloat16(h0[(size_t)(rb + row) * 100 + u]);
    }
    for (int i = tid; i < 64 * 26; i += 512) {
        const int row = i / 26, cc = i - row * 26;
        At[row][110 + cc] = __float2bfloat16(cc == 0 ? 1.0f : 0.0f);
    }
    {
        const int tt0 = dir ? 19 : 0;
        if (tid < 320) {
            const float v = x[(size_t)tt0 * (BTOT * 5) + (size_t)rb * 5 + tid];
            const int row = tid / 5, cc = tid - row * 5;
            const __hip_bfloat16 hi = __float2bfloat16(v);
            At[row][cc]     = hi;
            At[row][5 + cc] = __float2bfloat16(v - __bfloat162float(hi));
        }
    }
    __syncthreads();

    for (int t = 0; t < 20; ++t) {
        const int tt = dir ? (19 - t) : t;

        f32x4 acc[4][4];
        #pragma unroll
        for (int cti = 0; cti < 4; ++cti)
            #pragma unroll
            for (int rt = 0; rt < 4; ++rt)
                acc[cti][rt] = (f32x4){0.f, 0.f, 0.f, 0.f};

        #pragma unroll
        for (int kt = 0; kt < 4; ++kt) {
            bf16x8 afr[4];
            #pragma unroll
            for (int rt = 0; rt < 4; ++rt)
                afr[rt] = *reinterpret_cast<const bf16x8*>(
                    &At[rt * 16 + (l & 15)][kt * 32 + (l >> 4) * 8]);
            #pragma unroll
            for (int cti = 0; cti < 4; ++cti) {
                const int ct = w + 8 * cti;
                if (ct < 25) {
                    const size_t fo = ((size_t)(ct * 4 + kt) * 64 + l) * 8;
                    const bf16x8 bh = *reinterpret_cast<const bf16x8*>(BFhi == Bhi ? BFhi + fo : BBhi + fo);
                    const bf16x8 bl = *reinterpret_cast<const bf16x8*>(BFlo == Blo ? BFlo + fo : BBlo + fo);
                    #pragma unroll
                    for (int rt = 0; rt < 4; ++rt) {
                        acc[cti][rt] = __builtin_amdgcn_mfma_f32_16x16x32_bf16(
                            afr[rt], bh, acc[cti][rt], 0, 0, 0);
                        acc[cti][rt] = __builtin_amdgcn_mfma_f32_16x16x32_bf16(
                            afr[rt], bl, acc[cti][rt], 0, 0, 0);
                    }
                }
            }
        }

        float hval[4][4];
        #pragma unroll
        for (int cti = 0; cti < 4; ++cti) {
            const int ct = w + 8 * cti;
            if (ct < 25) {
                #pragma unroll
                for (int rt = 0; rt < 4; ++rt) {
                    #pragma unroll
                    for (int rr = 0; rr < 4; ++rr)
                        scr[w][(l >> 4) * 4 + rr][l & 15] = acc[cti][rt][rr];
                    const float g0 = scr[w][l >> 2][(l & 3) * 4 + 0];
                    const float g1 = scr[w][l >> 2][(l & 3) * 4 + 1];
                    const float g2 = scr[w][l >> 2][(l & 3) * 4 + 2];
                    const float g3 = scr[w][l >> 2][(l & 3) * 4 + 3];
                    const float ig = sig_(g0);
                    const float fg = sig_(g1);
                    const float gg = tanh_(g2);
                    const float og = sig_(g3);
                    const float cn = fmaf(fg, cst[cti][rt], ig * gg);
                    cst[cti][rt] = cn;
                    hval[cti][rt] = og * tanh_(cn);
                }
            }
        }
        __syncthreads();

        #pragma unroll
        for (int cti = 0; cti < 4; ++cti) {
            const int ct = w + 8 * cti;
            if (ct < 25) {
                #pragma unroll
                for (int rt = 0; rt < 4; ++rt) {
                    const __hip_bfloat16 hb = __float2bfloat16(hval[cti][rt]);
                    At[rt * 16 + (l >> 2)][10 + ct * 4 + (l & 3)] = hb;
                    Hout[((size_t)tt * 100 + ct * 4 + (l & 3)) * BTOT
                         + rb + rt * 16 + (l >> 2)] = hb;
                }
            }
        }
        if (t < 19) {
            const int ttn = dir ? (19 - (t + 1)) : (t + 1);
            if (tid < 320) {
                const float v = x[(size_t)ttn * (BTOT * 5) + (size_t)rb * 5 + tid];
                const int row = tid / 5, cc = tid - row * 5;
                const __hip_bfloat16 hi = __float2bfloat16(v);
                At[row][cc]     = hi;
                At[row][5 + cc] = __float2bfloat16(v - __bfloat162float(hi));
            }
        }
        __syncthreads();
    }
}

// ---------------------------------------------------------------------------
// Kernel 2 v3: MFMA middle LSTM, 16 waves (1024 thr), cti-outer (round-12
// structure, low live regs), fragment-order A (round-13, conflict-free).
// Wave w owns cts {w, w+16, w+32, w+48} (<50). Gates via wave-local two-pass
// 8-col transpose in scr[16][16][9]. LDS = 62,464 B. grid = 256.
// ---------------------------------------------------------------------------
__device__ __forceinline__ int aidx(int row, int c) {
    return (((row >> 4) * 13 + (c >> 5)) * 64 + ((c >> 3) & 3) * 16 + (row & 15)) * 8
           + (c & 7);
}

__global__ __launch_bounds__(1024, 4) void k_mid(
    const float* __restrict__ h0m, const float* __restrict__ c0m,
    const __hip_bfloat16* __restrict__ Bhi, const __hip_bfloat16* __restrict__ Blo,
    const __hip_bfloat16* __restrict__ HF, const __hip_bfloat16* __restrict__ HB,
    __hip_bfloat16* __restrict__ HM)
{
    __shared__ __hip_bfloat16 Af[4][13][64][8];   // 53,248 B
    __shared__ float scr[16][16][9];              //  9,216 B

    const int tid = threadIdx.x;
    const int l   = tid & 63;
    const int w   = tid >> 6;                     // wave 0..15
    const int rb  = blockIdx.x * 64;
    __hip_bfloat16* A = &Af[0][0][0][0];

    float cst[4][4], hval[4][4];
    #pragma unroll
    for (int cti = 0; cti < 4; ++cti) {
        const int ct = w + 16 * cti;
        if (ct < 50) {
            #pragma unroll
            for (int rt = 0; rt < 4; ++rt)
                cst[cti][rt] = c0m[(size_t)(rb + rt * 16 + (l >> 2)) * 200 + ct * 4 + (l & 3)];
        }
    }

    // init A: hm = bf16(h0m) (cols 200-399); pads (400-415); hf/hb[0] (0-199)
    for (int i = tid; i < 12800; i += 1024) {
        const int u = i % 200, rr = i / 200;
        A[aidx(rr, 200 + u)] = __float2bfloat16(h0m[(size_t)(rb + rr) * 200 + u]);
    }
    for (int i = tid; i < 1024; i += 1024) {
        const int rr = i >> 4, cc = i & 15;
        A[aidx(rr, 400 + cc)] = __float2bfloat16((cc == 15) ? 1.0f : 0.0f);
    }
    for (int i = tid; i < 6400; i += 1024) {
        const int rr = i & 63, u = i >> 6;
        A[aidx(rr, u)]       = HF[(size_t)u * BTOT + rb + rr];
        A[aidx(rr, 100 + u)] = HB[(size_t)u * BTOT + rb + rr];
    }
    __syncthreads();

    for (int t = 0; t < 20; ++t) {
        #pragma unroll
        for (int cti = 0; cti < 4; ++cti) {
            const int ct = w + 16 * cti;
            if (ct < 50) {
                f32x4 acc[4];
                #pragma unroll
                for (int rt = 0; rt < 4; ++rt) acc[rt] = (f32x4){0.f, 0.f, 0.f, 0.f};
                const __hip_bfloat16* bph = Bhi + ((size_t)ct * 13 * 64 + l) * 8;
                const __hip_bfloat16* bpl = Blo + ((size_t)ct * 13 * 64 + l) * 8;
                #pragma unroll
                for (int kt = 0; kt < 13; ++kt) {
                    const bf16x8 bh = *reinterpret_cast<const bf16x8*>(bph + kt * 512);
                    const bf16x8 bl = *reinterpret_cast<const bf16x8*>(bpl + kt * 512);
                    #pragma unroll
                    for (int rt = 0; rt < 4; ++rt) {
                        const bf16x8 a = *reinterpret_cast<const bf16x8*>(&Af[rt][kt][l][0]);
                        acc[rt] = __builtin_amdgcn_mfma_f32_16x16x32_bf16(a, bh, acc[rt], 0, 0, 0);
                        acc[rt] = __builtin_amdgcn_mfma_f32_16x16x32_bf16(a, bl, acc[rt], 0, 0, 0);
                    }
                }
                // gates: wave-local two-pass 8-col transpose (scr[w] = [16][9])
                const int lo16 = l & 15;
                const int rowq = l >> 2;
                const int gq   = l & 3;
                #pragma unroll
                for (int rt = 0; rt < 4; ++rt) {
                    const f32x4 v = acc[rt];
                    float g0 = 0.f, g1 = 0.f, g2 = 0.f, g3 = 0.f;
                    if (lo16 < 8) {                       // pass A: cols 0..7
                        #pragma unroll
                        for (int rr = 0; rr < 4; ++rr)
                            scr[w][(l >> 4) * 4 + rr][lo16] = v[rr];
                    }
                    __builtin_amdgcn_sched_barrier(0);
                    if (gq < 2) {
                        g0 = scr[w][rowq][gq * 4 + 0];
                        g1 = scr[w][rowq][gq * 4 + 1];
                        g2 = scr[w][rowq][gq * 4 + 2];
                        g3 = scr[w][rowq][gq * 4 + 3];
                    }
                    __builtin_amdgcn_sched_barrier(0);
                    if (lo16 >= 8) {                      // pass B: cols 8..15
                        #pragma unroll
                        for (int rr = 0; rr < 4; ++rr)
                            scr[w][(l >> 4) * 4 + rr][lo16 - 8] = v[rr];
                    }
                    __builtin_amdgcn_sched_barrier(0);
                    if (gq >= 2) {
                        g0 = scr[w][rowq][(gq - 2) * 4 + 0];
                        g1 = scr[w][rowq][(gq - 2) * 4 + 1];
                        g2 = scr[w][rowq][(gq - 2) * 4 + 2];
                        g3 = scr[w][rowq][(gq - 2) * 4 + 3];
                    }
                    __builtin_amdgcn_sched_barrier(0);
                    const float ig = sig_(g0);
                    const float fg = sig_(g1);
                    const float gg = tanh_(g2);
                    const float og = sig_(g3);
                    const float cn = fmaf(fg, cst[cti][rt], ig * gg);
                    cst[cti][rt] = cn;
                    hval[cti][rt] = og * tanh_(cn);
                }
            }
        }
        __syncthreads();           // all waves done reading A for step t

        // publish hm[t] into A cols 200-399
        #pragma unroll
        for (int cti = 0; cti < 4; ++cti) {
            const int ct = w + 16 * cti;
            if (ct < 50) {
                #pragma unroll
                for (int rt = 0; rt < 4; ++rt)
                    A[aidx(rt * 16 + (l >> 2), 200 + ct * 4 + (l & 3))] =
                        __float2bfloat16(hval[cti][rt]);
            }
        }
        // stage hf/hb[t+1] into cols 0-199
        if (t < 19) {
            const __hip_bfloat16* HFt = HF + (size_t)(t + 1) * 100 * BTOT + rb;
            const __hip_bfloat16* HBt = HB + (size_t)(t + 1) * 100 * BTOT + rb;
            for (int i = tid; i < 6400; i += 1024) {
                const int rr = i & 63, u = i >> 6;
                A[aidx(rr, u)]       = HFt[(size_t)u * BTOT + rr];
                A[aidx(rr, 100 + u)] = HBt[(size_t)u * BTOT + rr];
            }
        }
        __syncthreads();
    }

    // final h -> HM bf16 [b][u]
    for (int i = tid; i < 12800; i += 1024) {
        const int u = i % 200, rr = i / 200;
        HM[(size_t)(rb + rr) * 200 + u] = A[aidx(rr, 200 + u)];
    }
}

// ---------------------------------------------------------------------------
// Kernel 3 (PROVEN): dense + convT chain, zero-padded LDS tiles.
// ---------------------------------------------------------------------------
__global__ __launch_bounds__(256, 2) void k_head(
    const __hip_bfloat16* __restrict__ HM,
    const float* __restrict__ Wd, const float* __restrict__ bd,
    const float* __restrict__ w1, const float* __restrict__ b1,
    const float* __restrict__ w2, const float* __restrict__ b2,
    const float* __restrict__ w3, const float* __restrict__ b3,
    const float* __restrict__ g1, const float* __restrict__ be1,
    const float* __restrict__ m1, const float* __restrict__ v1,
    const float* __restrict__ g2, const float* __restrict__ be2,
    const float* __restrict__ m2, const float* __restrict__ v2,
    float* __restrict__ out)
{
    __shared__ float hm_s[200];
    __shared__ float y27p[29];
    __shared__ float t1p[128][58];
    __shared__ float t2p[64][110];
    __shared__ float sc1[128], sh1[128], sc2[64], sh2[64];

    const int tid = threadIdx.x;
    const int b   = blockIdx.x;

    if (tid < 200) hm_s[tid] = __bfloat162float(HM[(size_t)b * 200 + tid]);
    if (tid < 128) {
        const float s = g1[tid] * __frsqrt_rn(v1[tid] + 1e-5f);
        sc1[tid] = s; sh1[tid] = be1[tid] - m1[tid] * s;
    } else if (tid < 192) {
        const int cc = tid - 128;
        const float s = g2[cc] * __frsqrt_rn(v2[cc] + 1e-5f);
        sc2[cc] = s; sh2[cc] = be2[cc] - m2[cc] * s;
    }
    {
        const int co = tid >> 1;
        t1p[co][(tid & 1) ? 55 : 0] = 0.0f;
        if (tid < 128) { t1p[tid][56] = 0.0f; t1p[tid][57] = 0.0f; }
        if (tid < 64)  { t2p[tid][0] = 0.0f; t2p[tid][109] = 0.0f; }
        if (tid == 0)  { y27p[0] = 0.0f; y27p[28] = 0.0f; }
    }
    __syncthreads();

    if (tid < 27) {
        float a = bd[tid];
        const float* wr = Wd + tid * 200;
        for (int i = 0; i < 200; ++i) a = fmaf(hm_s[i], wr[i], a);
        y27p[tid + 1] = a;
    }
    __syncthreads();

    for (int idx = tid; idx < 128 * 54; idx += 256) {
        const int co = idx / 54;
        const int ll = idx - co * 54;
        const int q  = (ll + 1) >> 1;
        const float4 w = *reinterpret_cast<const float4*>(w1 + co * 4);
        const float wHI = (ll & 1) ? w.x : w.y;
        const float wLO = (ll & 1) ? w.z : w.w;
        float a = b1[co];
        a = fmaf(y27p[q + 1], wHI, a);
        a = fmaf(y27p[q],     wLO, a);
        a = fmaf(a, sc1[co], sh1[co]);
        t1p[co][ll + 1] = fmaxf(a, 0.0f);
    }
    __syncthreads();

    {
        const int co   = tid & 63;
        const int lseg = tid >> 6;
        const int l0   = lseg * 28;
        const int qb   = lseg * 14;
        float acc[28];
        const float bb = b2[co];
        #pragma unroll
        for (int j = 0; j < 28; ++j) acc[j] = bb;

        #pragma unroll 2
        for (int ci = 0; ci < 128; ++ci) {
            float tv[16];
            #pragma unroll
            for (int j = 0; j < 16; ++j) tv[j] = t1p[ci][qb + j];
            const float4 w = *reinterpret_cast<const float4*>(
                w2 + ((size_t)((ci << 6) + co) << 2));
            #pragma unroll
            for (int j = 0; j < 28; ++j) {
                const int qi = (j + 1) >> 1;
                const float wHI = (j & 1) ? w.x : w.y;
                const float wLO = (j & 1) ? w.z : w.w;
                acc[j] = fmaf(tv[qi + 1], wHI, acc[j]);
                acc[j] = fmaf(tv[qi],     wLO, acc[j]);
            }
        }
        const float s2 = sc2[co], h2 = sh2[co];
        #pragma unroll
        for (int j = 0; j < 28; ++j) {
            const int ll = l0 + j;
            if (ll < 108) t2p[co][ll + 1] = fmaxf(fmaf(acc[j], s2, h2), 0.0f);
        }
    }
    __syncthreads();

    if (tid < 216) {
        const int ll = tid;
        const int q = (ll + 1) >> 1;
        const bool odd = (ll & 1) != 0;
        float a = b3[0];
        #pragma unroll 4
        for (int ci = 0; ci < 64; ++ci) {
            const float4 w = *reinterpret_cast<const float4*>(w3 + ci * 4);
            const float wHI = odd ? w.x : w.y;
            const float wLO = odd ? w.z : w.w;
            a = fmaf(t2p[ci][q + 1], wHI, a);
            a = fmaf(t2p[ci][q],     wLO, a);
        }
        out[(size_t)b * 216 + ll] = a;
    }
}

// ---------------------------------------------------------------------------
extern "C" void kernel_launch(void* const* d_in, const int* in_sizes, int n_in,
                              void* d_out, int out_size, void* d_ws, size_t ws_size,
                              hipStream_t stream) {
    const float* x     = (const float*)d_in[0];
    const float* h0f   = (const float*)d_in[1];
    const float* c0f   = (const float*)d_in[2];
    const float* h0b   = (const float*)d_in[3];
    const float* c0b   = (const float*)d_in[4];
    const float* h0m   = (const float*)d_in[5];
    const float* c0m   = (const float*)d_in[6];
    const float* Wih_f = (const float*)d_in[7];
    const float* Whh_f = (const float*)d_in[8];
    const float* bih_f = (const float*)d_in[9];
    const float* bhh_f = (const float*)d_in[10];
    const float* Wih_b = (const float*)d_in[11];
    const float* Whh_b = (const float*)d_in[12];
    const float* bih_b = (const float*)d_in[13];
    const float* bhh_b = (const float*)d_in[14];
    const float* Wih_m = (const float*)d_in[15];
    const float* Whh_m = (const float*)d_in[16];
    const float* bih_m = (const float*)d_in[17];
    const float* bhh_m = (const float*)d_in[18];
    const float* Wd    = (const float*)d_in[19];
    const float* bd    = (const float*)d_in[20];
    const float* w1    = (const float*)d_in[21];
    const float* b1    = (const float*)d_in[22];
    const float* w2    = (const float*)d_in[23];
    const float* b2    = (const float*)d_in[24];
    const float* w3    = (const float*)d_in[25];
    const float* b3    = (const float*)d_in[26];
    const float* g1    = (const float*)d_in[27];
    const float* be1   = (const float*)d_in[28];
    const float* m1    = (const float*)d_in[29];
    const float* v1    = (const float*)d_in[30];
    const float* g2    = (const float*)d_in[31];
    const float* be2   = (const float*)d_in[32];
    const float* m2    = (const float*)d_in[33];
    const float* v2    = (const float*)d_in[34];

    // ws layout (bytes), total 139,366,400 <= proven 144,179,200:
    char* ws = (char*)d_ws;
    __hip_bfloat16* HF   = (__hip_bfloat16*)ws;
    __hip_bfloat16* HB   = (__hip_bfloat16*)(ws + 65536000);
    __hip_bfloat16* BhiM = (__hip_bfloat16*)(ws + 131072000);
    __hip_bfloat16* BloM = (__hip_bfloat16*)(ws + 131737600);
    __hip_bfloat16* BFhi = (__hip_bfloat16*)(ws + 132403200);
    __hip_bfloat16* BFlo = (__hip_bfloat16*)(ws + 132505600);
    __hip_bfloat16* BBhi = (__hip_bfloat16*)(ws + 132608000);
    __hip_bfloat16* BBlo = (__hip_bfloat16*)(ws + 132710400);
    __hip_bfloat16* HM   = (__hip_bfloat16*)(ws + 132812800);

    k_prep_mfma<<<(332800 + 255) / 256, 256, 0, stream>>>(
        Wih_m, Whh_m, bih_m, bhh_m, BhiM, BloM);
    k_prep_mfma100<<<(51200 + 255) / 256, 256, 0, stream>>>(
        Wih_f, Whh_f, bih_f, bhh_f, BFhi, BFlo);
    k_prep_mfma100<<<(51200 + 255) / 256, 256, 0, stream>>>(
        Wih_b, Whh_b, bih_b, bhh_b, BBhi, BBlo);

    k_lstm100<<<dim3(256, 2), 512, 0, stream>>>(
        x, h0f, c0f, h0b, c0b,
        BFhi, BFlo, BBhi, BBlo, HF, HB);

    k_mid<<<256, 1024, 0, stream>>>(
        h0m, c0m, BhiM, BloM, HF, HB, HM);

    k_head<<<16384, 256, 0, stream>>>(
        HM, Wd, bd, w1, b1, w2, b2, w3, b3,
        g1, be1, m1, v1, g2, be2, m2, v2, (float*)d_out);
}